// Round 6
// baseline (414.350 us; speedup 1.0000x reference)
//
#include <hip/hip_runtime.h>
#include <math.h>

#define DD 64
#define EDA 16

// packed B-fragment offsets (units of 64-lane short8 entries)
#define FR_E1 0
#define FR_E2 4
#define FR_N1 12
#define FR_N2 20
#define FR_O1 28
#define FR_O2 44
#define FR_TOT 52

#define PADH 72   // hid bf16 LDS row stride (ushort) for node/out kernels
#define PADF 68   // f32 LDS row stride (float)

// edge kernel strides
#define HS 72     // hid[e][h] stride in ushort (144B: 16B-aligned rows)
#define XS 72     // xls[e][o] stride in ushort
#define PF 68     // msg[e][o] stride in f32 (272B: 16B-aligned)

typedef unsigned int u32;
typedef __attribute__((ext_vector_type(8))) short short8;
typedef __attribute__((ext_vector_type(4))) float f32x4;

static __device__ __forceinline__ float silu(float v) {
    return v / (1.0f + __expf(-v));
}
static __device__ __forceinline__ unsigned short f2bf(float f) {
    unsigned u = __float_as_uint(f);
    unsigned r = u + 0x7FFFu + ((u >> 16) & 1u);   // RNE
    return (unsigned short)(r >> 16);
}
static __device__ __forceinline__ float bf2f(unsigned short u) {
    return __uint_as_float(((unsigned)u) << 16);
}
static __device__ __forceinline__ unsigned cvt_pk_bf16(float lo, float hi) {
    unsigned r;
    asm("v_cvt_pk_bf16_f32 %0, %1, %2" : "=v"(r) : "v"(lo), "v"(hi));
    return r;
}
// wave-local LDS fence: cross-lane LDS write->read within one wave (no block barrier)
static __device__ __forceinline__ void wave_lds_fence() {
    asm volatile("s_waitcnt lgkmcnt(0)" ::: "memory");
    __builtin_amdgcn_sched_barrier(0);
}

// ---------------- weight pre-pack into MFMA B-fragment layout ----------------
// B-frag (16x16x32): lane l holds B[k = s*32 + (l>>4)*8 + j][n = nt*16 + (l&15)]
// (identical register layout serves as A-frag of the TRANSPOSED matrix)
__global__ __launch_bounds__(256) void k_pack_w(
    const float* __restrict__ eW1, const float* __restrict__ eW2,
    const float* __restrict__ nW1, const float* __restrict__ nW2,
    const float* __restrict__ oW1, const float* __restrict__ oW2,
    unsigned short* __restrict__ wpk)
{
    int t = threadIdx.x;
    int nt = t >> 6, l = t & 63;
    int kc = l >> 4, n0 = l & 15;

    #pragma unroll
    for (int j = 0; j < 8; ++j) {
        int k = kc*8 + j;
        int orig = (k < 16) ? (9 + k) : ((k < 25) ? (k - 16) : -1);
        float v = (orig >= 0) ? eW1[orig*DD + nt*16 + n0] : 0.0f;
        wpk[((size_t)((FR_E1 + nt)*64 + l))*8 + j] = f2bf(v);
    }
    #pragma unroll
    for (int s = 0; s < 2; ++s) {
        #pragma unroll
        for (int j = 0; j < 8; ++j) {
            int k = s*32 + kc*8 + j;
            wpk[((size_t)((FR_E2 + s*4 + nt)*64 + l))*8 + j] = f2bf(eW2[k*DD + nt*16 + n0]);
            wpk[((size_t)((FR_N1 + s*4 + nt)*64 + l))*8 + j] = f2bf(nW1[k*DD + nt*16 + n0]);
            wpk[((size_t)((FR_N2 + s*4 + nt)*64 + l))*8 + j] = f2bf(nW2[k*DD + nt*16 + n0]);
            wpk[((size_t)((FR_O2 + s*4 + nt)*64 + l))*8 + j] = f2bf(oW2[k*DD + nt*16 + n0]);
        }
    }
    #pragma unroll
    for (int s = 0; s < 4; ++s) {
        #pragma unroll
        for (int j = 0; j < 8; ++j) {
            int k = s*32 + kc*8 + j;
            wpk[((size_t)((FR_O1 + s*4 + nt)*64 + l))*8 + j] = f2bf(oW1[k*DD + nt*16 + n0]);
        }
    }
}

// ---------------- histogram + scans ----------------
__global__ __launch_bounds__(256) void k_hist(
    const int* __restrict__ col, u32* __restrict__ cnt, int n_e)
{
    int g = blockIdx.x * 256 + threadIdx.x;
    int base = g * 4;
    if (base + 3 < n_e) {
        int4 c = ((const int4*)col)[g];
        atomicAdd(&cnt[c.x], 1u);
        atomicAdd(&cnt[c.y], 1u);
        atomicAdd(&cnt[c.z], 1u);
        atomicAdd(&cnt[c.w], 1u);
    } else {
        for (int e = base; e < n_e; ++e) atomicAdd(&cnt[col[e]], 1u);
    }
}

__global__ __launch_bounds__(256) void k_scan1(
    const u32* __restrict__ cnt, u32* __restrict__ bsum, int n)
{
    __shared__ u32 s[256];
    int i = blockIdx.x * 256 + threadIdx.x;
    s[threadIdx.x] = (i < n) ? cnt[i] : 0u;
    __syncthreads();
    for (int o = 128; o > 0; o >>= 1) {
        if (threadIdx.x < o) s[threadIdx.x] += s[threadIdx.x + o];
        __syncthreads();
    }
    if (threadIdx.x == 0) bsum[blockIdx.x] = s[0];
}

__global__ __launch_bounds__(512) void k_scan2(
    const u32* __restrict__ bsum, u32* __restrict__ boff, int nb)
{
    __shared__ u32 s[512];
    int t = threadIdx.x;
    u32 v = (t < nb) ? bsum[t] : 0u;
    s[t] = v;
    __syncthreads();
    for (int o = 1; o < 512; o <<= 1) {
        u32 a = (t >= o) ? s[t - o] : 0u;
        __syncthreads();
        s[t] += a;
        __syncthreads();
    }
    if (t < nb) boff[t] = s[t] - v;
}

__global__ __launch_bounds__(256) void k_scan3(
    const u32* __restrict__ cnt, const u32* __restrict__ boff,
    u32* __restrict__ wp, int n)
{
    __shared__ u32 s[256];
    int t = threadIdx.x;
    int i = blockIdx.x * 256 + t;
    u32 v = (i < n) ? cnt[i] : 0u;
    s[t] = v;
    __syncthreads();
    for (int o = 1; o < 256; o <<= 1) {
        u32 a = (t >= o) ? s[t - o] : 0u;
        __syncthreads();
        s[t] += a;
        __syncthreads();
    }
    if (i < n) wp[i] = boff[blockIdx.x] + s[t] - v;
}

// ---------------- counting-sort scatter: one packed 8B record per edge ------
// pack: lo = e(21) | r<<21 (low 11); hi = r>>11 (6) | c<<6 (17)
__global__ __launch_bounds__(256) void k_scatter(
    const int* __restrict__ row, const int* __restrict__ col,
    u32* __restrict__ wp, uint2* __restrict__ ce, int n_e)
{
    int e = blockIdx.x * 256 + threadIdx.x;
    if (e >= n_e) return;
    int c = col[e];
    int r = row[e];
    u32 p = atomicAdd(&wp[c], 1u);
    uint2 pk;
    pk.x = (u32)e | ((u32)r << 21);
    pk.y = ((u32)r >> 11) | ((u32)c << 6);
    ce[p] = pk;
}

// ---------------- MFMA node MLP: x (N,64) f32 -> x_tb (N,64) bf16 ----------------
__global__ __launch_bounds__(256, 2) void k_node_mfma(
    const float* __restrict__ x,
    const unsigned short* __restrict__ wpk,
    const float* __restrict__ b1, const float* __restrict__ b2,
    unsigned short* __restrict__ x_tb, int n)
{
    __shared__ __align__(16) unsigned short tile[4][16*PADH];
    const int tid  = threadIdx.x;
    const int wv   = tid >> 6;
    const int lane = tid & 63;
    const int kc   = lane >> 4;
    const int n0   = lane & 15;
    const int rbase = kc * 4;

    const short8* fb = (const short8*)wpk;
    short8 bw1[2][4], bw2[2][4];
    #pragma unroll
    for (int s = 0; s < 2; ++s)
        #pragma unroll
        for (int nt = 0; nt < 4; ++nt) {
            bw1[s][nt] = fb[(FR_N1 + s*4 + nt)*64 + lane];
            bw2[s][nt] = fb[(FR_N2 + s*4 + nt)*64 + lane];
        }
    float b1v[4], b2v[4];
    #pragma unroll
    for (int nt = 0; nt < 4; ++nt) { b1v[nt] = b1[nt*16 + n0]; b2v[nt] = b2[nt*16 + n0]; }

    const int base = blockIdx.x*64 + wv*16;
    int rc = min(base + n0, n - 1);
    const float* xr = x + (size_t)rc * DD;

    short8 a[2];
    #pragma unroll
    for (int m = 0; m < 2; ++m) {
        float4 u0 = *(const float4*)(xr + m*32 + kc*8);
        float4 u1 = *(const float4*)(xr + m*32 + kc*8 + 4);
        unsigned* au = (unsigned*)&a[m];
        au[0] = cvt_pk_bf16(u0.x, u0.y);
        au[1] = cvt_pk_bf16(u0.z, u0.w);
        au[2] = cvt_pk_bf16(u1.x, u1.y);
        au[3] = cvt_pk_bf16(u1.z, u1.w);
    }

    f32x4 zz = {0.f, 0.f, 0.f, 0.f};
    f32x4 hacc[4] = {zz, zz, zz, zz};
    #pragma unroll
    for (int m = 0; m < 2; ++m)
        #pragma unroll
        for (int nt = 0; nt < 4; ++nt)
            hacc[nt] = __builtin_amdgcn_mfma_f32_16x16x32_bf16(a[m], bw1[m][nt], hacc[nt], 0, 0, 0);

    #pragma unroll
    for (int nt = 0; nt < 4; ++nt)
        #pragma unroll
        for (int r = 0; r < 4; ++r)
            tile[wv][(rbase + r)*PADH + nt*16 + n0] = f2bf(silu(hacc[nt][r] + b1v[nt]));
    __syncthreads();

    short8 a2_0 = *(const short8*)&tile[wv][n0*PADH +  0 + kc*8];
    short8 a2_1 = *(const short8*)&tile[wv][n0*PADH + 32 + kc*8];
    f32x4 oacc[4];
    #pragma unroll
    for (int nt = 0; nt < 4; ++nt) {
        oacc[nt] = __builtin_amdgcn_mfma_f32_16x16x32_bf16(a2_0, bw2[0][nt], zz, 0, 0, 0);
        oacc[nt] = __builtin_amdgcn_mfma_f32_16x16x32_bf16(a2_1, bw2[1][nt], oacc[nt], 0, 0, 0);
    }
    __syncthreads();

    #pragma unroll
    for (int nt = 0; nt < 4; ++nt)
        #pragma unroll
        for (int r = 0; r < 4; ++r)
            tile[wv][(rbase + r)*PADH + nt*16 + n0] = f2bf(oacc[nt][r] + b2v[nt]);
    __syncthreads();

    int ei = lane >> 2, q = lane & 3;
    int er = base + ei;
    if (er < n) {
        uint4* dst = (uint4*)(x_tb + (size_t)er * DD);
        dst[q]     = *(const uint4*)&tile[wv][ei*PADH + q*8];
        dst[q + 4] = *(const uint4*)&tile[wv][ei*PADH + (q + 4)*8];
    }
}

// ---------------- fused edge kernel: swapped GEMMs, wave-private tiles ------
// 256 threads = 4 waves; each wave owns 64 consecutive sorted-edge slots,
// processed as 4 sub-tiles of 16 edges. No block barriers (wave-local fences).
__global__ __launch_bounds__(256, 3) void k_edge_fused(
    const float* __restrict__ pos,
    const float* __restrict__ edge_attr,
    const uint2* __restrict__ ce,
    const unsigned short* __restrict__ x_tb,
    const unsigned short* __restrict__ wpk,
    const float* __restrict__ b1, const float* __restrict__ b2,
    float* __restrict__ agg, int n_e)
{
    __shared__ __align__(16) unsigned short hid_s[4][16*HS];  // [edge][hidden]
    __shared__ __align__(16) float          msg_s[4][16*PF];  // [edge][outf]
    __shared__ __align__(16) unsigned short xls[4][16*XS];    // [edge][outf] bf16
    __shared__ __align__(16) u32            sh_s[4][64*8];    // per-edge packed SH bf16 (5 used)
    __shared__ int r_s[4][64], c_s[4][64], e_s[4][64];

    const int tid  = threadIdx.x;
    const int wv   = tid >> 6;
    const int lane = tid & 63;
    const int kc   = lane >> 4;
    const int n0   = lane & 15;

    const short8* fb = (const short8*)wpk;
    short8 bw1[4], bw2[2][4];
    #pragma unroll
    for (int nt = 0; nt < 4; ++nt) bw1[nt] = fb[(FR_E1 + nt)*64 + lane];
    #pragma unroll
    for (int s = 0; s < 2; ++s)
        #pragma unroll
        for (int nt = 0; nt < 4; ++nt) bw2[s][nt] = fb[(FR_E2 + s*4 + nt)*64 + lane];

    // swapped-C layout: lane holds features o = nt*16 + kc*4 + r  -> float4 per nt
    float4 b1q[4], b2q[4];
    #pragma unroll
    for (int nt = 0; nt < 4; ++nt) {
        b1q[nt] = *(const float4*)(b1 + nt*16 + kc*4);
        b2q[nt] = *(const float4*)(b2 + nt*16 + kc*4);
    }

    const int gbase = blockIdx.x*256 + wv*64;
    int g  = gbase + lane;
    int gc = min(g, n_e - 1);
    uint2 pk = ce[gc];
    int eo = pk.x & 0x1FFFFF;
    int rw = (pk.x >> 21) | ((pk.y & 0x3Fu) << 11);
    int cl = (int)(pk.y >> 6);
    r_s[wv][lane] = rw; c_s[wv][lane] = cl; e_s[wv][lane] = eo;

    // ---- geometry + SH: once per edge (this lane) ----
    float ax = pos[3*rw+0] - pos[3*cl+0];
    float ay = pos[3*rw+1] - pos[3*cl+1];
    float az = pos[3*rw+2] - pos[3*cl+2];
    float len = sqrtf(fmaf(ax,ax, fmaf(ay,ay, az*az)) + 1e-12f);
    float dx = ax/len, dy = ay/len, dz = az/len;
    float n2 = sqrtf(fmaf(dx,dx, fmaf(dy,dy, dz*dz)));
    float inv = 1.0f/(n2 + 1e-10f);
    dx *= inv; dy *= inv; dz *= inv;

    float sh0 = 0.28209479177387814f;
    float sh1 = 0.4886025119029199f*dy;
    float sh2 = 0.4886025119029199f*dz;
    float sh3 = 0.4886025119029199f*dx;
    float sh4 = 1.0925484305920792f*dx*dy;
    float sh5 = 1.0925484305920792f*dy*dz;
    float sh6 = 0.31539156525252005f*(3.0f*dz*dz - 1.0f);
    float sh7 = 1.0925484305920792f*dx*dz;
    float sh8 = 0.5462742152960396f*(dx*dx - dy*dy);

    {
        uint4 sp;
        sp.x = cvt_pk_bf16(sh0, sh1);
        sp.y = cvt_pk_bf16(sh2, sh3);
        sp.z = cvt_pk_bf16(sh4, sh5);
        sp.w = cvt_pk_bf16(sh6, sh7);
        u32* d = &sh_s[wv][lane*8];
        *(uint4*)d = sp;
        d[4] = cvt_pk_bf16(sh8, 0.0f);
    }

    f32x4 zz = {0.f, 0.f, 0.f, 0.f};

    #pragma unroll 1
    for (int t = 0; t < 4; ++t) {
        // protect prior subtile's LDS reads (and top-phase writes) before overwrite
        wave_lds_fence();

        // ---- stage x_tb rows of the 16 edges (4 lanes/row, 32B each); zero invalid
        {
            int lr = lane >> 2, ch = lane & 3;
            int rrow = r_s[wv][t*16 + lr];
            bool v = (gbase + t*16 + lr) < n_e;
            const uint4* src = (const uint4*)(x_tb + (size_t)rrow * DD);
            uint4 v0 = src[ch*2], v1 = src[ch*2 + 1];
            if (!v) { v0 = make_uint4(0,0,0,0); v1 = make_uint4(0,0,0,0); }
            *(uint4*)&xls[wv][lr*XS + ch*16]     = v0;
            *(uint4*)&xls[wv][lr*XS + ch*16 + 8] = v1;
        }

        // ---- feature B-frag: lane holds F[e=n0][k=kc*8+j]
        short8 af;
        unsigned* au = (unsigned*)&af;
        if (kc < 2) {
            int ea = e_s[wv][t*16 + n0];
            const float4* ap = (const float4*)(edge_attr + (size_t)ea*EDA + kc*8);
            float4 a0 = ap[0], a1 = ap[1];
            au[0] = cvt_pk_bf16(a0.x, a0.y);
            au[1] = cvt_pk_bf16(a0.z, a0.w);
            au[2] = cvt_pk_bf16(a1.x, a1.y);
            au[3] = cvt_pk_bf16(a1.z, a1.w);
        } else if (kc == 2) {
            uint4 s4 = *(const uint4*)&sh_s[wv][(t*16 + n0)*8];
            au[0] = s4.x; au[1] = s4.y; au[2] = s4.z; au[3] = s4.w;
        } else {
            au[0] = sh_s[wv][(t*16 + n0)*8 + 4];
            au[1] = 0; au[2] = 0; au[3] = 0;
        }

        // ---- GEMM1 swapped: hid^T = W1^T x F^T; lane gets hid[e=n0][h=nt*16+kc*4+r]
        f32x4 hacc[4];
        #pragma unroll
        for (int nt = 0; nt < 4; ++nt)
            hacc[nt] = __builtin_amdgcn_mfma_f32_16x16x32_bf16(bw1[nt], af, zz, 0, 0, 0);

        #pragma unroll
        for (int nt = 0; nt < 4; ++nt) {
            float h0 = silu(hacc[nt][0] + b1q[nt].x);
            float h1 = silu(hacc[nt][1] + b1q[nt].y);
            float h2 = silu(hacc[nt][2] + b1q[nt].z);
            float h3 = silu(hacc[nt][3] + b1q[nt].w);
            uint2 pr;
            pr.x = cvt_pk_bf16(h0, h1);
            pr.y = cvt_pk_bf16(h2, h3);
            *(uint2*)&hid_s[wv][n0*HS + nt*16 + kc*4] = pr;
        }
        wave_lds_fence();

        // ---- GEMM2 swapped: out^T = W2^T x hid^T
        short8 bf0 = *(const short8*)&hid_s[wv][n0*HS +  0 + kc*8];
        short8 bf1 = *(const short8*)&hid_s[wv][n0*HS + 32 + kc*8];
        f32x4 oacc[4];
        #pragma unroll
        for (int nt = 0; nt < 4; ++nt) {
            oacc[nt] = __builtin_amdgcn_mfma_f32_16x16x32_bf16(bw2[0][nt], bf0, zz, 0, 0, 0);
            oacc[nt] = __builtin_amdgcn_mfma_f32_16x16x32_bf16(bw2[1][nt], bf1, oacc[nt], 0, 0, 0);
        }

        // ---- epilogue: msg[e=n0][o] = (out + b2[o]) * x_t[row][o]
        #pragma unroll
        for (int nt = 0; nt < 4; ++nt) {
            uint2 xv = *(const uint2*)&xls[wv][n0*XS + nt*16 + kc*4];
            float x0 = bf2f((unsigned short)(xv.x));
            float x1 = bf2f((unsigned short)(xv.x >> 16));
            float x2 = bf2f((unsigned short)(xv.y));
            float x3 = bf2f((unsigned short)(xv.y >> 16));
            float4 m;
            m.x = (oacc[nt][0] + b2q[nt].x) * x0;
            m.y = (oacc[nt][1] + b2q[nt].y) * x1;
            m.z = (oacc[nt][2] + b2q[nt].z) * x2;
            m.w = (oacc[nt][3] + b2q[nt].w) * x3;
            *(float4*)&msg_s[wv][n0*PF + nt*16 + kc*4] = m;
        }
        wave_lds_fence();

        // ---- segmented reduce over 16 sorted rows; lane = feature
        {
            const int* cs = &c_s[wv][t*16];
            float acc = 0.0f;
            #pragma unroll
            for (int r = 0; r < 16; ++r) {
                acc += msg_s[wv][r*PF + lane];
                int cur = cs[r];
                if (r == 15) {
                    unsafeAtomicAdd(&agg[(size_t)cur*DD + lane], acc);
                } else if (cs[r+1] != cur) {
                    unsafeAtomicAdd(&agg[(size_t)cur*DD + lane], acc);
                    acc = 0.0f;
                }
            }
        }
    }
}

// ---------------- MFMA out MLP (+ /cnt) + fused BN partial sums ----------------
__global__ __launch_bounds__(256, 2) void k_out_mfma(
    const float* __restrict__ agg, const u32* __restrict__ cnt,
    const float* __restrict__ x,
    const unsigned short* __restrict__ wpk,
    const float* __restrict__ b1, const float* __restrict__ b2,
    float* __restrict__ h, float* __restrict__ sums, int n)
{
    __shared__ __align__(16) unsigned short htile[4][16*PADH];
    __shared__ __align__(16) float otile[4][16*PADF];
    const int tid  = threadIdx.x;
    const int wv   = tid >> 6;
    const int lane = tid & 63;
    const int kc   = lane >> 4;
    const int n0   = lane & 15;
    const int rbase = kc * 4;

    const short8* fb = (const short8*)wpk;
    short8 bw1[4][4], bw2[2][4];
    #pragma unroll
    for (int s = 0; s < 4; ++s)
        #pragma unroll
        for (int nt = 0; nt < 4; ++nt) bw1[s][nt] = fb[(FR_O1 + s*4 + nt)*64 + lane];
    #pragma unroll
    for (int s = 0; s < 2; ++s)
        #pragma unroll
        for (int nt = 0; nt < 4; ++nt) bw2[s][nt] = fb[(FR_O2 + s*4 + nt)*64 + lane];

    float b1v[4], b2v[4];
    #pragma unroll
    for (int nt = 0; nt < 4; ++nt) { b1v[nt] = b1[nt*16 + n0]; b2v[nt] = b2[nt*16 + n0]; }

    const int base = blockIdx.x*64 + wv*16;
    int rc = min(base + n0, n - 1);
    const float* ar = agg + (size_t)rc * DD;
    const float* xr = x   + (size_t)rc * DD;
    float invc = 1.0f / fmaxf((float)cnt[rc], 1.0f);

    short8 a[4];
    #pragma unroll
    for (int m = 0; m < 4; ++m) {
        const float* src = (m < 2) ? (ar + m*32 + kc*8) : (xr + (m-2)*32 + kc*8);
        float4 u0 = *(const float4*)(src);
        float4 u1 = *(const float4*)(src + 4);
        if (m < 2) {
            u0.x*=invc; u0.y*=invc; u0.z*=invc; u0.w*=invc;
            u1.x*=invc; u1.y*=invc; u1.z*=invc; u1.w*=invc;
        }
        unsigned* au = (unsigned*)&a[m];
        au[0] = cvt_pk_bf16(u0.x, u0.y);
        au[1] = cvt_pk_bf16(u0.z, u0.w);
        au[2] = cvt_pk_bf16(u1.x, u1.y);
        au[3] = cvt_pk_bf16(u1.z, u1.w);
    }

    f32x4 zz = {0.f, 0.f, 0.f, 0.f};
    f32x4 hacc[4] = {zz, zz, zz, zz};
    #pragma unroll
    for (int m = 0; m < 4; ++m)
        #pragma unroll
        for (int nt = 0; nt < 4; ++nt)
            hacc[nt] = __builtin_amdgcn_mfma_f32_16x16x32_bf16(a[m], bw1[m][nt], hacc[nt], 0, 0, 0);

    #pragma unroll
    for (int nt = 0; nt < 4; ++nt)
        #pragma unroll
        for (int r = 0; r < 4; ++r)
            htile[wv][(rbase + r)*PADH + nt*16 + n0] = f2bf(silu(hacc[nt][r] + b1v[nt]));
    __syncthreads();

    short8 a2_0 = *(const short8*)&htile[wv][n0*PADH +  0 + kc*8];
    short8 a2_1 = *(const short8*)&htile[wv][n0*PADH + 32 + kc*8];
    f32x4 oacc[4];
    #pragma unroll
    for (int nt = 0; nt < 4; ++nt) {
        oacc[nt] = __builtin_amdgcn_mfma_f32_16x16x32_bf16(a2_0, bw2[0][nt], zz, 0, 0, 0);
        oacc[nt] = __builtin_amdgcn_mfma_f32_16x16x32_bf16(a2_1, bw2[1][nt], oacc[nt], 0, 0, 0);
    }

    #pragma unroll
    for (int nt = 0; nt < 4; ++nt)
        #pragma unroll
        for (int r = 0; r < 4; ++r)
            otile[wv][(rbase + r)*PADF + nt*16 + n0] = oacc[nt][r] + b2v[nt];
    __syncthreads();

    int ei = lane >> 2, q = lane & 3;
    int er = base + ei;
    if (er < n) {
        float4* dst = (float4*)(h + (size_t)er * DD);
        #pragma unroll
        for (int k = 0; k < 4; ++k)
            dst[q + 4*k] = *(const float4*)&otile[wv][ei*PADF + (q + 4*k)*4];
    }

    if (tid < 64) {
        int f = tid;
        float s = 0.f, qq = 0.f;
        #pragma unroll
        for (int w = 0; w < 4; ++w) {
            int base_w = blockIdx.x*64 + w*16;
            int nv = n - base_w;
            nv = nv < 0 ? 0 : (nv > 16 ? 16 : nv);
            for (int r = 0; r < nv; ++r) {
                float v = otile[w][r*PADF + f];
                s += v; qq = fmaf(v, v, qq);
            }
        }
        unsafeAtomicAdd(&sums[f], s);
        unsafeAtomicAdd(&sums[DD + f], qq);
    }
}

// ---------------- BN finalize + normalize ----------------
__global__ void k_bn_finalize(const float* __restrict__ sums,
                              const float* __restrict__ gamma, const float* __restrict__ beta,
                              float* __restrict__ ss, float inv_n)
{
    int j = threadIdx.x;   // 64 threads
    float m = sums[j] * inv_n;
    float var = sums[DD+j] * inv_n - m*m;
    float sc = gamma[j] * rsqrtf(var + 1e-5f);
    ss[j] = sc;
    ss[DD+j] = beta[j] - m*sc;
}

__global__ __launch_bounds__(256) void k_bn_norm(
    float* __restrict__ h, const float* __restrict__ ss, int total4)
{
    int g = blockIdx.x*256 + threadIdx.x;
    if (g >= total4) return;
    int f0 = (g*4) & (DD-1);
    float4 v = ((const float4*)h)[g];
    v.x = fmaf(v.x, ss[f0+0], ss[DD+f0+0]);
    v.y = fmaf(v.y, ss[f0+1], ss[DD+f0+1]);
    v.z = fmaf(v.z, ss[f0+2], ss[DD+f0+2]);
    v.w = fmaf(v.w, ss[f0+3], ss[DD+f0+3]);
    ((float4*)h)[g] = v;
}

static inline size_t al16(size_t v) { return (v + 15) & ~(size_t)15; }

extern "C" void kernel_launch(void* const* d_in, const int* in_sizes, int n_in,
                              void* d_out, int out_size, void* d_ws, size_t ws_size,
                              hipStream_t stream)
{
    const float* x         = (const float*)d_in[0];
    const float* pos       = (const float*)d_in[1];
    const float* edge_attr = (const float*)d_in[2];
    const int*   row       = (const int*)d_in[3];
    const int*   col       = (const int*)d_in[4];
    const float* nW1 = (const float*)d_in[5];
    const float* nb1 = (const float*)d_in[6];
    const float* nW2 = (const float*)d_in[7];
    const float* nb2 = (const float*)d_in[8];
    const float* eW1 = (const float*)d_in[9];
    const float* eb1 = (const float*)d_in[10];
    const float* eW2 = (const float*)d_in[11];
    const float* eb2 = (const float*)d_in[12];
    const float* oW1 = (const float*)d_in[13];
    const float* ob1 = (const float*)d_in[14];
    const float* oW2 = (const float*)d_in[15];
    const float* ob2 = (const float*)d_in[16];
    const float* gamma = (const float*)d_in[17];
    const float* beta  = (const float*)d_in[18];

    const int N = in_sizes[0] / DD;   // 100000  (< 2^17 for packing)
    const int E = in_sizes[3];        // 1600000 (< 2^21 for packing)
    const int NB = (N + 255) / 256;   // 391

    float* hout = (float*)d_out;
    char* ws = (char*)d_ws;

    size_t o_xtb  = 0;
    size_t o_cnt  = o_xtb  + (size_t)N*DD*2;
    size_t o_sums = o_cnt  + (size_t)N*4;
    size_t o_agg  = o_sums + 128*4;
    size_t o_ss   = o_agg  + (size_t)N*DD*4;
    size_t o_wp   = o_ss   + 128*4;
    size_t o_bsum = o_wp   + (size_t)N*4;
    size_t o_boff = al16(o_bsum + (size_t)NB*4);
    size_t o_wpk  = al16(o_boff + (size_t)NB*4);
    size_t o_ce   = al16(o_wpk + (size_t)FR_TOT*64*8*2);
    size_t need   = o_ce + (size_t)E*8;

    if (ws_size < need) return;

    unsigned short* x_tb = (unsigned short*)(ws + o_xtb);
    u32*   cnt  = (u32*)(ws + o_cnt);
    float* sums = (float*)(ws + o_sums);
    float* agg  = (float*)(ws + o_agg);
    float* ssb  = (float*)(ws + o_ss);
    u32*   wp   = (u32*)(ws + o_wp);
    u32*   bsum = (u32*)(ws + o_bsum);
    u32*   boff = (u32*)(ws + o_boff);
    unsigned short* wpk = (unsigned short*)(ws + o_wpk);
    uint2* ce   = (uint2*)(ws + o_ce);

    // zero cnt + sums + agg (contiguous)
    hipMemsetAsync(cnt, 0, (size_t)N*4 + 128*4 + (size_t)N*DD*4, stream);

    k_pack_w<<<1, 256, 0, stream>>>(eW1, eW2, nW1, nW2, oW1, oW2, wpk);
    k_hist <<<(E/4 + 255)/256, 256, 0, stream>>>(col, cnt, E);
    k_scan1<<<NB, 256, 0, stream>>>(cnt, bsum, N);
    k_scan2<<<1, 512, 0, stream>>>(bsum, boff, NB);
    k_scan3<<<NB, 256, 0, stream>>>(cnt, boff, wp, N);
    k_scatter<<<(E + 255)/256, 256, 0, stream>>>(row, col, wp, ce, E);
    k_node_mfma<<<(N + 63)/64, 256, 0, stream>>>(x, wpk, nb1, nb2, x_tb, N);
    k_edge_fused<<<(E + 255)/256, 256, 0, stream>>>(pos, edge_attr, ce, x_tb,
                                                    wpk, eb1, eb2, agg, E);
    k_out_mfma<<<(N + 63)/64, 256, 0, stream>>>(agg, cnt, x, wpk, ob1, ob2, hout, sums, N);
    k_bn_finalize<<<1, 64, 0, stream>>>(sums, gamma, beta, ssb, 1.0f/(float)N);
    k_bn_norm<<<(N*DD/4 + 255)/256, 256, 0, stream>>>(hout, ssb, N*DD/4);
}

// Round 7
// 408.727 us; speedup vs baseline: 1.0138x; 1.0138x over previous
//
#include <hip/hip_runtime.h>
#include <math.h>

#define DD 64
#define EDA 16

// packed B-fragment offsets (units of 64-lane short8 entries)
#define FR_E1 0
#define FR_E2 4
#define FR_N1 12
#define FR_N2 20
#define FR_O1 28
#define FR_O2 44
#define FR_TOT 52

#define PADH 72   // hid bf16 LDS row stride (ushort) for node/out kernels
#define PADF 68   // f32 LDS row stride (float)

// edge kernel strides
#define HS 72     // hid[e][h] stride in ushort (144B; 144%16==0 for b128 reads)
#define PF 68     // msg[e][f] stride in f32 (272B)

typedef unsigned int u32;
typedef __attribute__((ext_vector_type(8))) short short8;
typedef __attribute__((ext_vector_type(4))) float f32x4;

static __device__ __forceinline__ float silu(float v) {
    return v / (1.0f + __expf(-v));
}
static __device__ __forceinline__ unsigned short f2bf(float f) {
    unsigned u = __float_as_uint(f);
    unsigned r = u + 0x7FFFu + ((u >> 16) & 1u);   // RNE
    return (unsigned short)(r >> 16);
}
static __device__ __forceinline__ float bf2f(unsigned short u) {
    return __uint_as_float(((unsigned)u) << 16);
}
static __device__ __forceinline__ unsigned cvt_pk_bf16(float lo, float hi) {
    unsigned r;
    asm("v_cvt_pk_bf16_f32 %0, %1, %2" : "=v"(r) : "v"(lo), "v"(hi));
    return r;
}
static __device__ __forceinline__ int bperm(int idx_lane, int v) {
    return __builtin_amdgcn_ds_bpermute(idx_lane << 2, v);
}
// LDS write->read fence within a wave (rule #18: sched_barrier after lgkmcnt)
static __device__ __forceinline__ void wave_lds_fence() {
    asm volatile("s_waitcnt lgkmcnt(0)" ::: "memory");
    __builtin_amdgcn_sched_barrier(0);
}

// ---------------- weight pre-pack into MFMA B-fragment layout ----------------
// B-frag (16x16x32): lane l holds B[k = s*32 + (l>>4)*8 + j][n = nt*16 + (l&15)]
// (identical register layout serves as A-frag of the TRANSPOSED matrix)
__global__ __launch_bounds__(256) void k_pack_w(
    const float* __restrict__ eW1, const float* __restrict__ eW2,
    const float* __restrict__ nW1, const float* __restrict__ nW2,
    const float* __restrict__ oW1, const float* __restrict__ oW2,
    unsigned short* __restrict__ wpk)
{
    int t = threadIdx.x;
    int nt = t >> 6, l = t & 63;
    int kc = l >> 4, n0 = l & 15;

    #pragma unroll
    for (int j = 0; j < 8; ++j) {
        int k = kc*8 + j;
        int orig = (k < 16) ? (9 + k) : ((k < 25) ? (k - 16) : -1);
        float v = (orig >= 0) ? eW1[orig*DD + nt*16 + n0] : 0.0f;
        wpk[((size_t)((FR_E1 + nt)*64 + l))*8 + j] = f2bf(v);
    }
    #pragma unroll
    for (int s = 0; s < 2; ++s) {
        #pragma unroll
        for (int j = 0; j < 8; ++j) {
            int k = s*32 + kc*8 + j;
            wpk[((size_t)((FR_E2 + s*4 + nt)*64 + l))*8 + j] = f2bf(eW2[k*DD + nt*16 + n0]);
            wpk[((size_t)((FR_N1 + s*4 + nt)*64 + l))*8 + j] = f2bf(nW1[k*DD + nt*16 + n0]);
            wpk[((size_t)((FR_N2 + s*4 + nt)*64 + l))*8 + j] = f2bf(nW2[k*DD + nt*16 + n0]);
            wpk[((size_t)((FR_O2 + s*4 + nt)*64 + l))*8 + j] = f2bf(oW2[k*DD + nt*16 + n0]);
        }
    }
    #pragma unroll
    for (int s = 0; s < 4; ++s) {
        #pragma unroll
        for (int j = 0; j < 8; ++j) {
            int k = s*32 + kc*8 + j;
            wpk[((size_t)((FR_O1 + s*4 + nt)*64 + l))*8 + j] = f2bf(oW1[k*DD + nt*16 + n0]);
        }
    }
}

// ---------------- histogram + scans ----------------
__global__ __launch_bounds__(256) void k_hist(
    const int* __restrict__ col, u32* __restrict__ cnt, int n_e)
{
    int g = blockIdx.x * 256 + threadIdx.x;
    int base = g * 4;
    if (base + 3 < n_e) {
        int4 c = ((const int4*)col)[g];
        atomicAdd(&cnt[c.x], 1u);
        atomicAdd(&cnt[c.y], 1u);
        atomicAdd(&cnt[c.z], 1u);
        atomicAdd(&cnt[c.w], 1u);
    } else {
        for (int e = base; e < n_e; ++e) atomicAdd(&cnt[col[e]], 1u);
    }
}

__global__ __launch_bounds__(256) void k_scan1(
    const u32* __restrict__ cnt, u32* __restrict__ bsum, int n)
{
    __shared__ u32 s[256];
    int i = blockIdx.x * 256 + threadIdx.x;
    s[threadIdx.x] = (i < n) ? cnt[i] : 0u;
    __syncthreads();
    for (int o = 128; o > 0; o >>= 1) {
        if (threadIdx.x < o) s[threadIdx.x] += s[threadIdx.x + o];
        __syncthreads();
    }
    if (threadIdx.x == 0) bsum[blockIdx.x] = s[0];
}

__global__ __launch_bounds__(512) void k_scan2(
    const u32* __restrict__ bsum, u32* __restrict__ boff, int nb)
{
    __shared__ u32 s[512];
    int t = threadIdx.x;
    u32 v = (t < nb) ? bsum[t] : 0u;
    s[t] = v;
    __syncthreads();
    for (int o = 1; o < 512; o <<= 1) {
        u32 a = (t >= o) ? s[t - o] : 0u;
        __syncthreads();
        s[t] += a;
        __syncthreads();
    }
    if (t < nb) boff[t] = s[t] - v;
}

__global__ __launch_bounds__(256) void k_scan3(
    const u32* __restrict__ cnt, const u32* __restrict__ boff,
    u32* __restrict__ wp, int n)
{
    __shared__ u32 s[256];
    int t = threadIdx.x;
    int i = blockIdx.x * 256 + t;
    u32 v = (i < n) ? cnt[i] : 0u;
    s[t] = v;
    __syncthreads();
    for (int o = 1; o < 256; o <<= 1) {
        u32 a = (t >= o) ? s[t - o] : 0u;
        __syncthreads();
        s[t] += a;
        __syncthreads();
    }
    if (i < n) wp[i] = boff[blockIdx.x] + s[t] - v;
}

// ---------------- counting-sort scatter: one packed 8B record per edge ------
// pack: lo = e(21) | r<<21 (low 11); hi = r>>11 (6) | c<<6 (17)
__global__ __launch_bounds__(256) void k_scatter(
    const int* __restrict__ row, const int* __restrict__ col,
    u32* __restrict__ wp, uint2* __restrict__ ce, int n_e)
{
    int e = blockIdx.x * 256 + threadIdx.x;
    if (e >= n_e) return;
    int c = col[e];
    int r = row[e];
    u32 p = atomicAdd(&wp[c], 1u);
    uint2 pk;
    pk.x = (u32)e | ((u32)r << 21);
    pk.y = ((u32)r >> 11) | ((u32)c << 6);
    ce[p] = pk;
}

// ---------------- MFMA node MLP: x (N,64) f32 -> x_tb (N,64) bf16 ----------------
__global__ __launch_bounds__(256, 2) void k_node_mfma(
    const float* __restrict__ x,
    const unsigned short* __restrict__ wpk,
    const float* __restrict__ b1, const float* __restrict__ b2,
    unsigned short* __restrict__ x_tb, int n)
{
    __shared__ __align__(16) unsigned short tile[4][16*PADH];
    const int tid  = threadIdx.x;
    const int wv   = tid >> 6;
    const int lane = tid & 63;
    const int kc   = lane >> 4;
    const int n0   = lane & 15;
    const int rbase = kc * 4;

    const short8* fb = (const short8*)wpk;
    short8 bw1[2][4], bw2[2][4];
    #pragma unroll
    for (int s = 0; s < 2; ++s)
        #pragma unroll
        for (int nt = 0; nt < 4; ++nt) {
            bw1[s][nt] = fb[(FR_N1 + s*4 + nt)*64 + lane];
            bw2[s][nt] = fb[(FR_N2 + s*4 + nt)*64 + lane];
        }
    float b1v[4], b2v[4];
    #pragma unroll
    for (int nt = 0; nt < 4; ++nt) { b1v[nt] = b1[nt*16 + n0]; b2v[nt] = b2[nt*16 + n0]; }

    const int base = blockIdx.x*64 + wv*16;
    int rc = min(base + n0, n - 1);
    const float* xr = x + (size_t)rc * DD;

    short8 a[2];
    #pragma unroll
    for (int m = 0; m < 2; ++m) {
        float4 u0 = *(const float4*)(xr + m*32 + kc*8);
        float4 u1 = *(const float4*)(xr + m*32 + kc*8 + 4);
        unsigned* au = (unsigned*)&a[m];
        au[0] = cvt_pk_bf16(u0.x, u0.y);
        au[1] = cvt_pk_bf16(u0.z, u0.w);
        au[2] = cvt_pk_bf16(u1.x, u1.y);
        au[3] = cvt_pk_bf16(u1.z, u1.w);
    }

    f32x4 zz = {0.f, 0.f, 0.f, 0.f};
    f32x4 hacc[4] = {zz, zz, zz, zz};
    #pragma unroll
    for (int m = 0; m < 2; ++m)
        #pragma unroll
        for (int nt = 0; nt < 4; ++nt)
            hacc[nt] = __builtin_amdgcn_mfma_f32_16x16x32_bf16(a[m], bw1[m][nt], hacc[nt], 0, 0, 0);

    #pragma unroll
    for (int nt = 0; nt < 4; ++nt)
        #pragma unroll
        for (int r = 0; r < 4; ++r)
            tile[wv][(rbase + r)*PADH + nt*16 + n0] = f2bf(silu(hacc[nt][r] + b1v[nt]));
    __syncthreads();

    short8 a2_0 = *(const short8*)&tile[wv][n0*PADH +  0 + kc*8];
    short8 a2_1 = *(const short8*)&tile[wv][n0*PADH + 32 + kc*8];
    f32x4 oacc[4];
    #pragma unroll
    for (int nt = 0; nt < 4; ++nt) {
        oacc[nt] = __builtin_amdgcn_mfma_f32_16x16x32_bf16(a2_0, bw2[0][nt], zz, 0, 0, 0);
        oacc[nt] = __builtin_amdgcn_mfma_f32_16x16x32_bf16(a2_1, bw2[1][nt], oacc[nt], 0, 0, 0);
    }
    __syncthreads();

    #pragma unroll
    for (int nt = 0; nt < 4; ++nt)
        #pragma unroll
        for (int r = 0; r < 4; ++r)
            tile[wv][(rbase + r)*PADH + nt*16 + n0] = f2bf(oacc[nt][r] + b2v[nt]);
    __syncthreads();

    int ei = lane >> 2, q = lane & 3;
    int er = base + ei;
    if (er < n) {
        uint4* dst = (uint4*)(x_tb + (size_t)er * DD);
        dst[q]     = *(const uint4*)&tile[wv][ei*PADH + q*8];
        dst[q + 4] = *(const uint4*)&tile[wv][ei*PADH + (q + 4)*8];
    }
}

// ---------------- fused edge kernel: swapped GEMMs, minimal LDS -------------
// 256 threads = 4 waves; wave owns 64 sorted slots, 4 sub-tiles of 16 edges.
// LDS: msg transpose + hid transpose only. SH/cols/x_t live in registers.
__global__ __launch_bounds__(256, 3) void k_edge_fused(
    const float* __restrict__ pos,
    const float* __restrict__ edge_attr,
    const uint2* __restrict__ ce,
    const unsigned short* __restrict__ x_tb,
    const unsigned short* __restrict__ wpk,
    const float* __restrict__ b1, const float* __restrict__ b2,
    float* __restrict__ agg, int n_e)
{
    __shared__ __align__(16) unsigned short hid_s[4][16*HS];  // 9216 B
    __shared__ __align__(16) float          msg_s[4][16*PF];  // 17408 B

    const int tid  = threadIdx.x;
    const int wv   = tid >> 6;
    const int lane = tid & 63;
    const int kc   = lane >> 4;
    const int n0   = lane & 15;

    const short8* fb = (const short8*)wpk;
    short8 bw1[4], bw2[2][4];
    #pragma unroll
    for (int nt = 0; nt < 4; ++nt) bw1[nt] = fb[(FR_E1 + nt)*64 + lane];
    #pragma unroll
    for (int s = 0; s < 2; ++s)
        #pragma unroll
        for (int nt = 0; nt < 4; ++nt) bw2[s][nt] = fb[(FR_E2 + s*4 + nt)*64 + lane];

    // swapped-C layout: lane holds features f = nt*16 + kc*4 + r
    float4 b1q[4], b2q[4];
    #pragma unroll
    for (int nt = 0; nt < 4; ++nt) {
        b1q[nt] = *(const float4*)(b1 + nt*16 + kc*4);
        b2q[nt] = *(const float4*)(b2 + nt*16 + kc*4);
    }

    const int gbase = blockIdx.x*256 + wv*64;
    int g  = gbase + lane;
    int gc = min(g, n_e - 1);
    uint2 pk = ce[gc];
    int eo = (int)(pk.x & 0x1FFFFFu);
    int rw = (int)((pk.x >> 21) | ((pk.y & 0x3Fu) << 11));
    int cl = (int)(pk.y >> 6);

    // ---- geometry + SH: once per edge (this lane), packed to bf16 regs ----
    float ax = pos[3*rw+0] - pos[3*cl+0];
    float ay = pos[3*rw+1] - pos[3*cl+1];
    float az = pos[3*rw+2] - pos[3*cl+2];
    float len = sqrtf(fmaf(ax,ax, fmaf(ay,ay, az*az)) + 1e-12f);
    float dx = ax/len, dy = ay/len, dz = az/len;
    float n2 = sqrtf(fmaf(dx,dx, fmaf(dy,dy, dz*dz)));
    float inv = 1.0f/(n2 + 1e-10f);
    dx *= inv; dy *= inv; dz *= inv;

    u32 shp01 = cvt_pk_bf16(0.28209479177387814f, 0.4886025119029199f*dy);
    u32 shp23 = cvt_pk_bf16(0.4886025119029199f*dz, 0.4886025119029199f*dx);
    u32 shp45 = cvt_pk_bf16(1.0925484305920792f*dx*dy, 1.0925484305920792f*dy*dz);
    u32 shp67 = cvt_pk_bf16(0.31539156525252005f*(3.0f*dz*dz - 1.0f),
                            1.0925484305920792f*dx*dz);
    u32 shp8  = cvt_pk_bf16(0.5462742152960396f*(dx*dx - dy*dy), 0.0f);

    f32x4 zz = {0.f, 0.f, 0.f, 0.f};

    #pragma unroll 1
    for (int t = 0; t < 4; ++t) {
        const int le = t*16 + n0;          // this lane's frag column edge (local)
        bool valid = (gbase + le) < n_e;

        // ---- cross-lane broadcasts (all lanes active) ----
        int ea  = bperm(le, eo);
        int rv  = bperm(le, rw);
        u32 s01 = (u32)bperm(le, (int)shp01);
        u32 s23 = (u32)bperm(le, (int)shp23);
        u32 s45 = (u32)bperm(le, (int)shp45);
        u32 s67 = (u32)bperm(le, (int)shp67);
        u32 s8  = (u32)bperm(le, (int)shp8);

        // ---- x_t[row] gather straight to registers (issued before GEMM1) ----
        const unsigned short* xrow = x_tb + (size_t)rv * DD;
        uint2 xv0 = *(const uint2*)(xrow +  0 + kc*4);
        uint2 xv1 = *(const uint2*)(xrow + 16 + kc*4);
        uint2 xv2 = *(const uint2*)(xrow + 32 + kc*4);
        uint2 xv3 = *(const uint2*)(xrow + 48 + kc*4);
        if (!valid) {
            xv0.x = xv0.y = xv1.x = xv1.y = 0u;
            xv2.x = xv2.y = xv3.x = xv3.y = 0u;
        }

        // ---- feature B-frag: lane holds F[e = le][k = kc*8 + j] ----
        short8 af;
        unsigned* au = (unsigned*)&af;
        if (kc < 2) {
            const float4* ap = (const float4*)(edge_attr + (size_t)ea*EDA + kc*8);
            float4 a0 = ap[0], a1 = ap[1];
            au[0] = cvt_pk_bf16(a0.x, a0.y);
            au[1] = cvt_pk_bf16(a0.z, a0.w);
            au[2] = cvt_pk_bf16(a1.x, a1.y);
            au[3] = cvt_pk_bf16(a1.z, a1.w);
        } else if (kc == 2) {
            au[0] = s01; au[1] = s23; au[2] = s45; au[3] = s67;
        } else {
            au[0] = s8; au[1] = 0u; au[2] = 0u; au[3] = 0u;
        }

        // ---- GEMM1 swapped: lane gets hid[e=n0][f=nt*16+kc*4+r] ----
        f32x4 hacc[4];
        #pragma unroll
        for (int nt = 0; nt < 4; ++nt)
            hacc[nt] = __builtin_amdgcn_mfma_f32_16x16x32_bf16(bw1[nt], af, zz, 0, 0, 0);

        #pragma unroll
        for (int nt = 0; nt < 4; ++nt) {
            float h0 = silu(hacc[nt][0] + b1q[nt].x);
            float h1 = silu(hacc[nt][1] + b1q[nt].y);
            float h2 = silu(hacc[nt][2] + b1q[nt].z);
            float h3 = silu(hacc[nt][3] + b1q[nt].w);
            uint2 pr;
            pr.x = cvt_pk_bf16(h0, h1);
            pr.y = cvt_pk_bf16(h2, h3);
            *(uint2*)&hid_s[wv][n0*HS + nt*16 + kc*4] = pr;
        }
        wave_lds_fence();

        // ---- GEMM2 swapped: out^T = W2^T x hid^T ----
        short8 bf0 = *(const short8*)&hid_s[wv][n0*HS +  0 + kc*8];
        short8 bf1 = *(const short8*)&hid_s[wv][n0*HS + 32 + kc*8];
        f32x4 oacc[4];
        #pragma unroll
        for (int nt = 0; nt < 4; ++nt) {
            oacc[nt] = __builtin_amdgcn_mfma_f32_16x16x32_bf16(bw2[0][nt], bf0, zz, 0, 0, 0);
            oacc[nt] = __builtin_amdgcn_mfma_f32_16x16x32_bf16(bw2[1][nt], bf1, oacc[nt], 0, 0, 0);
        }

        // ---- epilogue: msg[e=n0][f] = (out + b2[f]) * x_t[row][f] ----
        {
            float4 m;
            m.x = (oacc[0][0] + b2q[0].x) * bf2f((unsigned short)(xv0.x));
            m.y = (oacc[0][1] + b2q[0].y) * bf2f((unsigned short)(xv0.x >> 16));
            m.z = (oacc[0][2] + b2q[0].z) * bf2f((unsigned short)(xv0.y));
            m.w = (oacc[0][3] + b2q[0].w) * bf2f((unsigned short)(xv0.y >> 16));
            *(float4*)&msg_s[wv][n0*PF +  0 + kc*4] = m;
            m.x = (oacc[1][0] + b2q[1].x) * bf2f((unsigned short)(xv1.x));
            m.y = (oacc[1][1] + b2q[1].y) * bf2f((unsigned short)(xv1.x >> 16));
            m.z = (oacc[1][2] + b2q[1].z) * bf2f((unsigned short)(xv1.y));
            m.w = (oacc[1][3] + b2q[1].w) * bf2f((unsigned short)(xv1.y >> 16));
            *(float4*)&msg_s[wv][n0*PF + 16 + kc*4] = m;
            m.x = (oacc[2][0] + b2q[2].x) * bf2f((unsigned short)(xv2.x));
            m.y = (oacc[2][1] + b2q[2].y) * bf2f((unsigned short)(xv2.x >> 16));
            m.z = (oacc[2][2] + b2q[2].z) * bf2f((unsigned short)(xv2.y));
            m.w = (oacc[2][3] + b2q[2].w) * bf2f((unsigned short)(xv2.y >> 16));
            *(float4*)&msg_s[wv][n0*PF + 32 + kc*4] = m;
            m.x = (oacc[3][0] + b2q[3].x) * bf2f((unsigned short)(xv3.x));
            m.y = (oacc[3][1] + b2q[3].y) * bf2f((unsigned short)(xv3.x >> 16));
            m.z = (oacc[3][2] + b2q[3].z) * bf2f((unsigned short)(xv3.y));
            m.w = (oacc[3][3] + b2q[3].w) * bf2f((unsigned short)(xv3.y >> 16));
            *(float4*)&msg_s[wv][n0*PF + 48 + kc*4] = m;
        }
        wave_lds_fence();

        // ---- segmented reduce: lane = feature; cols via readlane (SGPR) ----
        {
            float acc = 0.0f;
            int cur = __builtin_amdgcn_readlane(cl, t*16 + 0);
            #pragma unroll
            for (int r = 0; r < 16; ++r) {
                acc += msg_s[wv][r*PF + lane];
                int nxt = (r < 15) ? __builtin_amdgcn_readlane(cl, t*16 + r + 1) : -1;
                if (nxt != cur) {
                    unsafeAtomicAdd(&agg[(size_t)cur*DD + lane], acc);
                    acc = 0.0f;
                    cur = nxt;
                }
            }
        }
    }
}

// ---------------- MFMA out MLP (+ /cnt) + fused BN partial sums ----------------
__global__ __launch_bounds__(256, 2) void k_out_mfma(
    const float* __restrict__ agg, const u32* __restrict__ cnt,
    const float* __restrict__ x,
    const unsigned short* __restrict__ wpk,
    const float* __restrict__ b1, const float* __restrict__ b2,
    float* __restrict__ h, float* __restrict__ sums, int n)
{
    __shared__ __align__(16) unsigned short htile[4][16*PADH];
    __shared__ __align__(16) float otile[4][16*PADF];
    const int tid  = threadIdx.x;
    const int wv   = tid >> 6;
    const int lane = tid & 63;
    const int kc   = lane >> 4;
    const int n0   = lane & 15;
    const int rbase = kc * 4;

    const short8* fb = (const short8*)wpk;
    short8 bw1[4][4], bw2[2][4];
    #pragma unroll
    for (int s = 0; s < 4; ++s)
        #pragma unroll
        for (int nt = 0; nt < 4; ++nt) bw1[s][nt] = fb[(FR_O1 + s*4 + nt)*64 + lane];
    #pragma unroll
    for (int s = 0; s < 2; ++s)
        #pragma unroll
        for (int nt = 0; nt < 4; ++nt) bw2[s][nt] = fb[(FR_O2 + s*4 + nt)*64 + lane];

    float b1v[4], b2v[4];
    #pragma unroll
    for (int nt = 0; nt < 4; ++nt) { b1v[nt] = b1[nt*16 + n0]; b2v[nt] = b2[nt*16 + n0]; }

    const int base = blockIdx.x*64 + wv*16;
    int rc = min(base + n0, n - 1);
    const float* ar = agg + (size_t)rc * DD;
    const float* xr = x   + (size_t)rc * DD;
    float invc = 1.0f / fmaxf((float)cnt[rc], 1.0f);

    short8 a[4];
    #pragma unroll
    for (int m = 0; m < 4; ++m) {
        const float* src = (m < 2) ? (ar + m*32 + kc*8) : (xr + (m-2)*32 + kc*8);
        float4 u0 = *(const float4*)(src);
        float4 u1 = *(const float4*)(src + 4);
        if (m < 2) {
            u0.x*=invc; u0.y*=invc; u0.z*=invc; u0.w*=invc;
            u1.x*=invc; u1.y*=invc; u1.z*=invc; u1.w*=invc;
        }
        unsigned* au = (unsigned*)&a[m];
        au[0] = cvt_pk_bf16(u0.x, u0.y);
        au[1] = cvt_pk_bf16(u0.z, u0.w);
        au[2] = cvt_pk_bf16(u1.x, u1.y);
        au[3] = cvt_pk_bf16(u1.z, u1.w);
    }

    f32x4 zz = {0.f, 0.f, 0.f, 0.f};
    f32x4 hacc[4] = {zz, zz, zz, zz};
    #pragma unroll
    for (int m = 0; m < 4; ++m)
        #pragma unroll
        for (int nt = 0; nt < 4; ++nt)
            hacc[nt] = __builtin_amdgcn_mfma_f32_16x16x32_bf16(a[m], bw1[m][nt], hacc[nt], 0, 0, 0);

    #pragma unroll
    for (int nt = 0; nt < 4; ++nt)
        #pragma unroll
        for (int r = 0; r < 4; ++r)
            htile[wv][(rbase + r)*PADH + nt*16 + n0] = f2bf(silu(hacc[nt][r] + b1v[nt]));
    __syncthreads();

    short8 a2_0 = *(const short8*)&htile[wv][n0*PADH +  0 + kc*8];
    short8 a2_1 = *(const short8*)&htile[wv][n0*PADH + 32 + kc*8];
    f32x4 oacc[4];
    #pragma unroll
    for (int nt = 0; nt < 4; ++nt) {
        oacc[nt] = __builtin_amdgcn_mfma_f32_16x16x32_bf16(a2_0, bw2[0][nt], zz, 0, 0, 0);
        oacc[nt] = __builtin_amdgcn_mfma_f32_16x16x32_bf16(a2_1, bw2[1][nt], oacc[nt], 0, 0, 0);
    }

    #pragma unroll
    for (int nt = 0; nt < 4; ++nt)
        #pragma unroll
        for (int r = 0; r < 4; ++r)
            otile[wv][(rbase + r)*PADF + nt*16 + n0] = oacc[nt][r] + b2v[nt];
    __syncthreads();

    int ei = lane >> 2, q = lane & 3;
    int er = base + ei;
    if (er < n) {
        float4* dst = (float4*)(h + (size_t)er * DD);
        #pragma unroll
        for (int k = 0; k < 4; ++k)
            dst[q + 4*k] = *(const float4*)&otile[wv][ei*PADF + (q + 4*k)*4];
    }

    if (tid < 64) {
        int f = tid;
        float s = 0.f, qq = 0.f;
        #pragma unroll
        for (int w = 0; w < 4; ++w) {
            int base_w = blockIdx.x*64 + w*16;
            int nv = n - base_w;
            nv = nv < 0 ? 0 : (nv > 16 ? 16 : nv);
            for (int r = 0; r < nv; ++r) {
                float v = otile[w][r*PADF + f];
                s += v; qq = fmaf(v, v, qq);
            }
        }
        unsafeAtomicAdd(&sums[f], s);
        unsafeAtomicAdd(&sums[DD + f], qq);
    }
}

// ---------------- BN finalize + normalize ----------------
__global__ void k_bn_finalize(const float* __restrict__ sums,
                              const float* __restrict__ gamma, const float* __restrict__ beta,
                              float* __restrict__ ss, float inv_n)
{
    int j = threadIdx.x;   // 64 threads
    float m = sums[j] * inv_n;
    float var = sums[DD+j] * inv_n - m*m;
    float sc = gamma[j] * rsqrtf(var + 1e-5f);
    ss[j] = sc;
    ss[DD+j] = beta[j] - m*sc;
}

__global__ __launch_bounds__(256) void k_bn_norm(
    float* __restrict__ h, const float* __restrict__ ss, int total4)
{
    int g = blockIdx.x*256 + threadIdx.x;
    if (g >= total4) return;
    int f0 = (g*4) & (DD-1);
    float4 v = ((const float4*)h)[g];
    v.x = fmaf(v.x, ss[f0+0], ss[DD+f0+0]);
    v.y = fmaf(v.y, ss[f0+1], ss[DD+f0+1]);
    v.z = fmaf(v.z, ss[f0+2], ss[DD+f0+2]);
    v.w = fmaf(v.w, ss[f0+3], ss[DD+f0+3]);
    ((float4*)h)[g] = v;
}

static inline size_t al16(size_t v) { return (v + 15) & ~(size_t)15; }

extern "C" void kernel_launch(void* const* d_in, const int* in_sizes, int n_in,
                              void* d_out, int out_size, void* d_ws, size_t ws_size,
                              hipStream_t stream)
{
    const float* x         = (const float*)d_in[0];
    const float* pos       = (const float*)d_in[1];
    const float* edge_attr = (const float*)d_in[2];
    const int*   row       = (const int*)d_in[3];
    const int*   col       = (const int*)d_in[4];
    const float* nW1 = (const float*)d_in[5];
    const float* nb1 = (const float*)d_in[6];
    const float* nW2 = (const float*)d_in[7];
    const float* nb2 = (const float*)d_in[8];
    const float* eW1 = (const float*)d_in[9];
    const float* eb1 = (const float*)d_in[10];
    const float* eW2 = (const float*)d_in[11];
    const float* eb2 = (const float*)d_in[12];
    const float* oW1 = (const float*)d_in[13];
    const float* ob1 = (const float*)d_in[14];
    const float* oW2 = (const float*)d_in[15];
    const float* ob2 = (const float*)d_in[16];
    const float* gamma = (const float*)d_in[17];
    const float* beta  = (const float*)d_in[18];

    const int N = in_sizes[0] / DD;   // 100000  (< 2^17 for packing)
    const int E = in_sizes[3];        // 1600000 (< 2^21 for packing)
    const int NB = (N + 255) / 256;   // 391

    float* hout = (float*)d_out;
    char* ws = (char*)d_ws;

    size_t o_xtb  = 0;
    size_t o_cnt  = o_xtb  + (size_t)N*DD*2;
    size_t o_sums = o_cnt  + (size_t)N*4;
    size_t o_agg  = o_sums + 128*4;
    size_t o_ss   = o_agg  + (size_t)N*DD*4;
    size_t o_wp   = o_ss   + 128*4;
    size_t o_bsum = o_wp   + (size_t)N*4;
    size_t o_boff = al16(o_bsum + (size_t)NB*4);
    size_t o_wpk  = al16(o_boff + (size_t)NB*4);
    size_t o_ce   = al16(o_wpk + (size_t)FR_TOT*64*8*2);
    size_t need   = o_ce + (size_t)E*8;

    if (ws_size < need) return;

    unsigned short* x_tb = (unsigned short*)(ws + o_xtb);
    u32*   cnt  = (u32*)(ws + o_cnt);
    float* sums = (float*)(ws + o_sums);
    float* agg  = (float*)(ws + o_agg);
    float* ssb  = (float*)(ws + o_ss);
    u32*   wp   = (u32*)(ws + o_wp);
    u32*   bsum = (u32*)(ws + o_bsum);
    u32*   boff = (u32*)(ws + o_boff);
    unsigned short* wpk = (unsigned short*)(ws + o_wpk);
    uint2* ce   = (uint2*)(ws + o_ce);

    // zero cnt + sums + agg (contiguous)
    hipMemsetAsync(cnt, 0, (size_t)N*4 + 128*4 + (size_t)N*DD*4, stream);

    k_pack_w<<<1, 256, 0, stream>>>(eW1, eW2, nW1, nW2, oW1, oW2, wpk);
    k_hist <<<(E/4 + 255)/256, 256, 0, stream>>>(col, cnt, E);
    k_scan1<<<NB, 256, 0, stream>>>(cnt, bsum, N);
    k_scan2<<<1, 512, 0, stream>>>(bsum, boff, NB);
    k_scan3<<<NB, 256, 0, stream>>>(cnt, boff, wp, N);
    k_scatter<<<(E + 255)/256, 256, 0, stream>>>(row, col, wp, ce, E);
    k_node_mfma<<<(N + 63)/64, 256, 0, stream>>>(x, wpk, nb1, nb2, x_tb, N);
    k_edge_fused<<<(E + 255)/256, 256, 0, stream>>>(pos, edge_attr, ce, x_tb,
                                                    wpk, eb1, eb2, agg, E);
    k_out_mfma<<<(N + 63)/64, 256, 0, stream>>>(agg, cnt, x, wpk, ob1, ob2, hout, sums, N);
    k_bn_finalize<<<1, 64, 0, stream>>>(sums, gamma, beta, ssb, 1.0f/(float)N);
    k_bn_norm<<<(N*DD/4 + 255)/256, 256, 0, stream>>>(hout, ssb, N*DD/4);
}